// Round 11
// baseline (89.130 us; speedup 1.0000x reference)
//
#include <hip/hip_runtime.h>

// Conv2d 5x5, C=3, O=1, stride 1, pad 2, N=256, H=W=224, +bias.
// R11: TXv=8 walker (amortize per-step overhead over 2x outputs).
//   Scoreboard: R7 (full unroll, VGPR 128, 4 waves/SIMD) = 55.5us best.
//   R8 fence / R9 launch-bounds / R10 rolled all LOST trading ILP for TLP.
//   So: keep the R7 regime, halve per-output overhead instead.
//   Per step: 12 slim loads (f2+f4+f4+f2 per ch, 48B) feed 8 outputs
//   -> 1.5 load-events/output (R7: 2.25), FMA:load 50:1 (R7: 33:1),
//   selects+addressing per output ~halved.
// Geometry: SY=4, NSTRIP=56, NCOL=28 -> 1568 blocks = 6.1/CU.
// Invariants kept: full unroll, NO launch_bounds min-arg, no sched fences,
// boundary-only row guards, aligned loads with edge-redirect (zero OOB).

namespace {

constexpr int Hc = 224, Wc = 224, Cc = 3;
constexpr int HW = Hc * Wc;
constexpr int CHW = Cc * HW;
constexpr int TXv = 8;              // outputs per thread in x
constexpr int NCOL = Wc / TXv;      // 28
constexpr int SY = 4;               // strip height per thread
constexpr int NSTRIP = Hc / SY;     // 56
constexpr int BLK = 256;
constexpr int NSTEP = SY + 4;       // 8 input rows per strip

__global__ __launch_bounds__(BLK) void conv5x5_r11(
    const float* __restrict__ x, const float* __restrict__ wl,
    const float* __restrict__ bptr, float* __restrict__ out) {
  const int t = blockIdx.x * BLK + threadIdx.x;
  // decode: col fastest (store coalescing), then strip, then n
  const int col = t % NCOL;
  const int rest = t / NCOL;
  const int strip = rest % NSTRIP;
  const int n = rest / NSTRIP;

  const int x0 = col * TXv;
  const int y0 = strip * SY;
  const bool lo = (col == 0);          // left image edge lane
  const bool hi = (col == NCOL - 1);   // right image edge lane (x0=216)

  // Weights: wave-uniform, compile-time offsets -> s_load (SGPRs).
  float w[Cc][5][5];
#pragma unroll
  for (int c = 0; c < Cc; ++c)
#pragma unroll
    for (int i = 0; i < 25; ++i) w[c][i / 5][i % 5] = wl[c * 25 + i];
  const float bias = bptr[0];

  const float* xb = x + (size_t)n * CHW + x0;
  float* ob = out + (size_t)n * HW + x0;

  // Window = x[x0-2 .. x0+9] (12 floats): f2 @ x0-2 (8B-aligned, x0%8==0),
  // f4 @ x0 (16B), f4 @ x0+4 (16B), f2 @ x0+8 (8B). Edge lanes redirect the
  // masked load inward (values zeroed in window build) -> zero OOB accesses.
  const int dL = lo ? 0 : -2;
  const int dR = hi ? 6 : 8;          // hi: x0+8=224 OOB -> x0+6 (zeroed)

  float4 acc[SY][2];                   // statically indexed; <=5 rows live
#pragma unroll
  for (int o = 0; o < SY; ++o) {
    acc[o][0] = make_float4(0.f, 0.f, 0.f, 0.f);
    acc[o][1] = make_float4(0.f, 0.f, 0.f, 0.f);
  }

  // Input row s (yi = y0-2+s) feeds output rows o = s-ky, ky in [0,4].
  // acc[o]: born s=o, stored s=o+4. All indices compile-time after unroll.
#pragma unroll
  for (int s = 0; s < NSTEP; ++s) {
    const int yi = y0 + s - 2;
    // Middle steps s in [2, SY+1]: 0 <= yi <= y0+SY-1 <= 223 always.
    const bool boundary = (s < 2) || (s >= SY + 2);

    bool rv = true;
    int yc = yi;
    if (boundary) {
      rv = (yi >= 0) && (yi < Hc);
      yc = yi < 0 ? 0 : (yi >= Hc ? Hc - 1 : yi);     // clamp address
    }

    // This step's 12 slim loads, issued together.
    float2 Lh[Cc], Rh[Cc]; float4 M0[Cc], M1[Cc];
#pragma unroll
    for (int c = 0; c < Cc; ++c) {
      const float* pc = xb + (size_t)c * HW + (size_t)yc * Wc;
      Lh[c] = *(const float2*)(pc + dL);
      M0[c] = *(const float4*)(pc);
      M1[c] = *(const float4*)(pc + 4);
      Rh[c] = *(const float2*)(pc + dR);
    }

#pragma unroll
    for (int c = 0; c < Cc; ++c) {
      const bool z = boundary && !rv;       // whole-row zero (y pad)
      float win[12];                         // win[j] = x[x0-2+j]
      win[0]  = (z || lo) ? 0.f : Lh[c].x;
      win[1]  = (z || lo) ? 0.f : Lh[c].y;
      win[2]  = z ? 0.f : M0[c].x;
      win[3]  = z ? 0.f : M0[c].y;
      win[4]  = z ? 0.f : M0[c].z;
      win[5]  = z ? 0.f : M0[c].w;
      win[6]  = z ? 0.f : M1[c].x;
      win[7]  = z ? 0.f : M1[c].y;
      win[8]  = z ? 0.f : M1[c].z;
      win[9]  = z ? 0.f : M1[c].w;
      win[10] = (z || hi) ? 0.f : Rh[c].x;
      win[11] = (z || hi) ? 0.f : Rh[c].y;
#pragma unroll
      for (int ky = 0; ky < 5; ++ky) {
        const int o = s - ky;
        if (o < 0 || o >= SY) continue;               // compile-time
#pragma unroll
        for (int kx = 0; kx < 5; ++kx) {
          const float wv = w[c][ky][kx];
          acc[o][0].x = fmaf(win[kx + 0], wv, acc[o][0].x);
          acc[o][0].y = fmaf(win[kx + 1], wv, acc[o][0].y);
          acc[o][0].z = fmaf(win[kx + 2], wv, acc[o][0].z);
          acc[o][0].w = fmaf(win[kx + 3], wv, acc[o][0].w);
          acc[o][1].x = fmaf(win[kx + 4], wv, acc[o][1].x);
          acc[o][1].y = fmaf(win[kx + 5], wv, acc[o][1].y);
          acc[o][1].z = fmaf(win[kx + 6], wv, acc[o][1].z);
          acc[o][1].w = fmaf(win[kx + 7], wv, acc[o][1].w);
        }
      }
    }

    if (s >= 4) {                     // output row s-4 complete
      const int o = s - 4;
      float* orow = ob + (size_t)(y0 + o) * Wc;
      float4 o0, o1;
      o0.x = acc[o][0].x + bias; o0.y = acc[o][0].y + bias;
      o0.z = acc[o][0].z + bias; o0.w = acc[o][0].w + bias;
      o1.x = acc[o][1].x + bias; o1.y = acc[o][1].y + bias;
      o1.z = acc[o][1].z + bias; o1.w = acc[o][1].w + bias;
      *(float4*)(orow)     = o0;
      *(float4*)(orow + 4) = o1;
    }
  }
}

}  // namespace

extern "C" void kernel_launch(void* const* d_in, const int* in_sizes, int n_in,
                              void* d_out, int out_size, void* d_ws, size_t ws_size,
                              hipStream_t stream) {
  const float* x  = (const float*)d_in[0];   // [N,3,224,224] f32
  const float* wl = (const float*)d_in[1];   // [1,75] f32
  const float* b  = (const float*)d_in[2];   // [1] f32
  float* out = (float*)d_out;                // [N,224,224] f32

  const int N = out_size / HW;               // 256
  const int total = N * NSTRIP * NCOL;       // 401408
  const int nblk = total / BLK;              // 1568 blocks = 6.1 per CU

  conv5x5_r11<<<nblk, BLK, 0, stream>>>(x, wl, b, out);
}

// Round 12
// 70.559 us; speedup vs baseline: 1.2632x; 1.2632x over previous
//
#include <hip/hip_runtime.h>

// Conv2d 5x5, C=3, O=1, stride 1, pad 2, N=256, H=W=224, +bias.
// R12: LDS-staged row-band design with global_load_lds (register-file bypass).
//   Register-only scoreboard: VGPR {36,52,96,128,168} -> best 55.5us at 128.
//   Deep load batching in VGPRs IS register pressure; LDS staging decouples:
//   batched async loads at zero VGPR cost + small compute live set + 5
//   blocks/CU of TLP.
// Structure:
//   - band = 8 output rows x full 224 width of one image; staged input =
//     12 rows x 224 x 3ch = 31.5 KB. Rows are CONTIGUOUS in global memory
//     -> staging is a linear memcpy: 10x1024B + 2x256B global_load_lds
//     chunks per channel, zero address math, no pad raggedness.
//   - boundary bands (b=0,27; 2 of 28) stage via guarded scalar writes that
//     embed true zero rows -> single uniform compute path.
//   - compute: 224 active threads (56 cols x 4 row-groups), thread = 4x2
//     outputs, windows read from LDS (b64/b128, stride-16B conflict-free),
//     75 FMA/output; acc in 8 regs.
//   - block walks 4 bands (rolled loop, barriers bound liveness); grid
//     256 images x 7 = 1792 blocks; LDS 31.5KB -> 5 blocks/CU resident.
// Budgets: HBM ~155+50 MB ~ 33us; VALU ~15us; LDS-read ~0.9GB ~ 13us.

namespace {

constexpr int Hc = 224, Wc = 224, Cc = 3;
constexpr int HW = Hc * Wc;
constexpr int CHW = Cc * HW;
constexpr int BAND = 8;              // output rows per band
constexpr int SROWS = BAND + 4;      // 12 staged input rows
constexpr int NBAND = Hc / BAND;     // 28
constexpr int BPB = 4;               // bands per block
constexpr int ROWB = Wc * 4;         // 896 bytes per row
constexpr int BLK = 256;

__device__ __forceinline__ void gl_lds16(const float* g, float* l) {
  __builtin_amdgcn_global_load_lds(
      (const __attribute__((address_space(1))) void*)g,
      (__attribute__((address_space(3))) void*)l, 16, 0, 0);
}
__device__ __forceinline__ void gl_lds4(const float* g, float* l) {
  __builtin_amdgcn_global_load_lds(
      (const __attribute__((address_space(1))) void*)g,
      (__attribute__((address_space(3))) void*)l, 4, 0, 0);
}

__global__ __launch_bounds__(BLK) void conv5x5_r12(
    const float* __restrict__ x, const float* __restrict__ wl,
    const float* __restrict__ bptr, float* __restrict__ out) {
  __shared__ __align__(16) float sm[Cc][SROWS][Wc];   // 32256 B

  const int tid = threadIdx.x;
  const int lane = tid & 63;
  const int wave = tid >> 6;
  const int bid = blockIdx.x;
  const int n = bid / (NBAND / BPB);       // image
  const int g = bid % (NBAND / BPB);       // band group (4 bands)

  // Weights: wave-uniform, compile-time offsets -> s_load (SGPRs).
  float w[Cc][5][5];
#pragma unroll
  for (int c = 0; c < Cc; ++c)
#pragma unroll
    for (int i = 0; i < 25; ++i) w[c][i / 5][i % 5] = wl[c * 25 + i];
  const float bias = bptr[0];

  const float* xn = x + (size_t)n * CHW;
  float* outn = out + (size_t)n * HW;

  // Compute-role decode: 224 active threads = 56 cols x 4 row-groups.
  const bool active = tid < 224;
  const int col = tid % 56;
  const int tg = tid / 56;
  const int x0 = col * 4;
  const int r0 = tg * 2;                   // local output rows r0, r0+1
  const bool lo = (col == 0);
  const bool hi = (col == 55);
  const int dL = lo ? 0 : -2;              // edge lanes redirect inward,
  const int dR = hi ? 0 : 4;               // values zeroed in window build

#pragma unroll 1
  for (int bb = 0; bb < BPB; ++bb) {
    const int b = g * BPB + bb;

    // ---- stage band b: LDS rows L hold global rows b*8-2+L ----
    if (b == 0 || b == NBAND - 1) {
      // Guarded scalar staging; writes true zeros for pad rows (y-pad
      // becomes real data -> single compute path for all bands).
      float* smf = &sm[0][0][0];
      for (int i = tid; i < Cc * SROWS * Wc; i += BLK) {
        const int ch = i / (SROWS * Wc);
        const int rem = i - ch * (SROWS * Wc);
        const int L = rem / Wc;
        const int xx = rem - L * Wc;
        const int gy = b * BAND - 2 + L;
        smf[i] = (gy >= 0 && gy < Hc) ? xn[ch * HW + gy * Wc + xx] : 0.f;
      }
    } else {
      // Fast path: 12 staged rows are fully in-bounds (b in [1,26]).
      // Per channel: contiguous 10752 B = 10x1024 + 2x256 chunks.
      const int sb = b * (BAND * ROWB) - 2 * ROWB;   // >= 5376
#pragma unroll
      for (int ch = 0; ch < Cc; ++ch) {
        const char* gch = (const char*)(xn + (size_t)ch * HW) + sb;
        char* lch = (char*)&sm[ch][0][0];
#pragma unroll
        for (int k = 0; k < 12; ++k) {
          if (((ch * 12 + k) & 3) != wave) continue;   // 9 chunks per wave
          if (k < 10) {
            const int off = k * 1024;
            gl_lds16((const float*)(gch + off + lane * 16),
                     (float*)(lch + off));
          } else {
            const int off = 10240 + (k - 10) * 256;
            gl_lds4((const float*)(gch + off + lane * 4),
                    (float*)(lch + off));
          }
        }
      }
    }
    __syncthreads();   // vmcnt drain + barrier -> LDS valid for all

    // ---- compute band b from LDS ----
    if (active) {
      float4 a0 = make_float4(0.f, 0.f, 0.f, 0.f);
      float4 a1 = make_float4(0.f, 0.f, 0.f, 0.f);
      // Thread reads LDS rows r0..r0+5; output local row R taps LDS rows
      // R..R+4 (ky = L - R). All jj/ch/kx indices compile-time.
#pragma unroll
      for (int jj = 0; jj < 6; ++jj) {
        const int L = r0 + jj;
#pragma unroll
        for (int ch = 0; ch < Cc; ++ch) {
          const float* rowp = &sm[ch][0][0] + L * Wc;
          const float2 Lh = *(const float2*)(rowp + x0 + dL);
          const float4 Mv = *(const float4*)(rowp + x0);
          const float2 Rh = *(const float2*)(rowp + x0 + dR);
          float win[8];                    // win[j] = x[x0-2+j]
          win[0] = lo ? 0.f : Lh.x;
          win[1] = lo ? 0.f : Lh.y;
          win[2] = Mv.x; win[3] = Mv.y; win[4] = Mv.z; win[5] = Mv.w;
          win[6] = hi ? 0.f : Rh.x;
          win[7] = hi ? 0.f : Rh.y;
          if (jj <= 4) {                   // rr=0: ky = jj
#pragma unroll
            for (int kx = 0; kx < 5; ++kx) {
              const float wv = w[ch][jj][kx];
              a0.x = fmaf(win[kx + 0], wv, a0.x);
              a0.y = fmaf(win[kx + 1], wv, a0.y);
              a0.z = fmaf(win[kx + 2], wv, a0.z);
              a0.w = fmaf(win[kx + 3], wv, a0.w);
            }
          }
          if (jj >= 1) {                   // rr=1: ky = jj-1
#pragma unroll
            for (int kx = 0; kx < 5; ++kx) {
              const float wv = w[ch][jj - 1][kx];
              a1.x = fmaf(win[kx + 0], wv, a1.x);
              a1.y = fmaf(win[kx + 1], wv, a1.y);
              a1.z = fmaf(win[kx + 2], wv, a1.z);
              a1.w = fmaf(win[kx + 3], wv, a1.w);
            }
          }
        }
      }
      const int gy0 = b * BAND + r0;
      float4 o0, o1;
      o0.x = a0.x + bias; o0.y = a0.y + bias;
      o0.z = a0.z + bias; o0.w = a0.w + bias;
      o1.x = a1.x + bias; o1.y = a1.y + bias;
      o1.z = a1.z + bias; o1.w = a1.w + bias;
      *(float4*)(outn + (size_t)gy0 * Wc + x0) = o0;
      *(float4*)(outn + (size_t)(gy0 + 1) * Wc + x0) = o1;
    }
    __syncthreads();   // all reads done before next band's stage overwrites
  }
}

}  // namespace

extern "C" void kernel_launch(void* const* d_in, const int* in_sizes, int n_in,
                              void* d_out, int out_size, void* d_ws, size_t ws_size,
                              hipStream_t stream) {
  const float* x  = (const float*)d_in[0];   // [N,3,224,224] f32
  const float* wl = (const float*)d_in[1];   // [1,75] f32
  const float* b  = (const float*)d_in[2];   // [1] f32
  float* out = (float*)d_out;                // [N,224,224] f32

  const int N = out_size / HW;               // 256
  const int nblk = N * (NBAND / BPB);        // 1792 blocks

  conv5x5_r12<<<nblk, BLK, 0, stream>>>(x, wl, b, out);
}

// Round 13
// 64.801 us; speedup vs baseline: 1.3754x; 1.0889x over previous
//
#include <hip/hip_runtime.h>

// Conv2d 5x5, C=3, O=1, stride 1, pad 2, N=256, H=W=224, +bias.
// R13: double-buffered LDS band pipeline, conflict-free all-b128 reads.
//   R12 post-mortem: FETCH 86MB (best traffic) but 1.13e7 LDS bank conflicts
//   (misaligned float2 edge reads: lanes c,c+8 same bank pair = 7-way) and
//   stage->barrier->compute serialization (occ 25%, no overlap).
// Fixes:
//   - LDS row holds global dwords shifted +4 (LDS j <-> global j-4), stride
//     256 dw (1024B). Window for col c = 3 aligned b128 @ dwords 4c/4c+4/4c+8,
//     win = {A.z,A.w,B.xyzw,C.x,C.y}: linear bank pattern, ~zero conflicts.
//     Left pad (dwords 0..3) / right garbage handled by existing lo/hi
//     cndmasks -> no pad init needed.
//   - double buffer (2 x 36864B = 73728B -> still 2 blocks/CU): per band,
//     sync -> issue stage(b+1) via global_load_lds (zero VGPR cost) ->
//     compute(b). Stage hides under compute; HBM-bound steady state ~38us.
//   - staging: row = 896B = 56 lanes x 16B, lane<56-masked gl_lds16, one
//     inst per (ch,row), 9 per wave. Boundary rows zeroed via vector store.
//   - bijective XCD swizzle (1792 = 8*224): an image's 7 blocks share L2.

namespace {

constexpr int Hc = 224, Wc = 224, Cc = 3;
constexpr int HW = Hc * Wc;
constexpr int CHW = Cc * HW;
constexpr int BAND = 8;               // output rows per band
constexpr int SROWS = BAND + 4;       // 12 staged input rows
constexpr int NBAND = Hc / BAND;      // 28
constexpr int BPB = 4;                // bands per block
constexpr int GPB = NBAND / BPB;      // 7 band-groups per image
constexpr int BLK = 256;
constexpr int RST = 256;              // LDS row stride (dwords) = 1024 B
constexpr int CST = SROWS * RST;      // channel stride (dwords)
constexpr int BUF = Cc * CST;         // 9216 dwords = 36864 B per buffer

__device__ __forceinline__ void gl_lds16(const float* g, float* l) {
  __builtin_amdgcn_global_load_lds(
      (const __attribute__((address_space(1))) void*)g,
      (__attribute__((address_space(3))) void*)l, 16, 0, 0);
}

__global__ __launch_bounds__(BLK) void conv5x5_r13(
    const float* __restrict__ x, const float* __restrict__ wl,
    const float* __restrict__ bptr, float* __restrict__ out) {
  __shared__ __align__(16) float sm[2 * BUF];   // 73728 B

  const int tid = threadIdx.x;
  const int lane = tid & 63;
  const int wv = tid >> 6;

  // Bijective XCD swizzle: nwg = 1792 = 8*224 -> consecutive work ids stay
  // on one XCD so an image's 7 blocks share halo rows in the same L2.
  const int nwg = gridDim.x;
  const int cpx = nwg >> 3;                       // 224 (nwg % 8 == 0)
  const int bid = (blockIdx.x & 7) * cpx + (blockIdx.x >> 3);

  const int n = bid / GPB;                        // image
  const int g = bid % GPB;                        // band group (4 bands)

  // Weights: wave-uniform, compile-time offsets -> SGPRs.
  float w[Cc][5][5];
#pragma unroll
  for (int c = 0; c < Cc; ++c)
#pragma unroll
    for (int i = 0; i < 25; ++i) w[c][i / 5][i % 5] = wl[c * 25 + i];
  const float bias = bptr[0];

  const float* xn = x + (size_t)n * CHW;
  float* outn = out + (size_t)n * HW;

  // Compute roles: 224 threads = 56 cols x 4 row-groups; thread = 4x2 outputs.
  const bool active = tid < 224;
  const int col = tid % 56;
  const int tg = tid / 56;
  const bool lo = (col == 0), hi = (col == 55);
  const int rdoff = tg * 2 * RST + col * 4;       // buffer-relative read base

  // Stage band bnd into buffer bufsel. 36 (ch,row) pairs; wave wv owns
  // p = wv + 4*i (wave-uniform branches only). LDS dest is the wave-uniform
  // row base; HW adds lane*16. Data occupies dwords [4..227] of each row
  // (global dword j at LDS j+4); lanes >= 56 masked off (row = 56 chunks).
#define STAGE(bnd, bufsel)                                                    \
  do {                                                                        \
    float* smb_ = sm + (bufsel) * BUF;                                        \
    _Pragma("unroll") for (int i_ = 0; i_ < 9; ++i_) {                        \
      const int p_ = wv + 4 * i_;                                             \
      const int ch_ = p_ / SROWS;                                             \
      const int r_ = p_ % SROWS;                                              \
      const int gy_ = (bnd) * BAND - 2 + r_;                                  \
      float* ld_ = smb_ + ch_ * CST + r_ * RST;                               \
      if (gy_ >= 0 && gy_ < Hc) {                                             \
        if (lane < 56)                                                        \
          gl_lds16(xn + (size_t)ch_ * HW + (size_t)gy_ * Wc + lane * 4,       \
                   ld_ + 4);                                                  \
      } else {                                                                \
        *(float4*)(ld_ + lane * 4) = make_float4(0.f, 0.f, 0.f, 0.f);         \
      }                                                                       \
    }                                                                         \
  } while (0)

  // Compute band bnd from buffer bufsel. Window for col c = 3 aligned b128:
  // A @ dword 4c (global 4c-4..4c-1), B @ 4c+4 (4c..4c+3), C @ 4c+8
  // (4c+4..4c+7); win[j] = global[4c-2+j] = {A.z,A.w,B.xyzw,C.x,C.y}.
  // lo: win0/1 = left pad (uninit) -> zeroed; hi: win6/7 = garbage -> zeroed.
#define COMPUTE(bnd, bufsel)                                                  \
  do {                                                                        \
    if (active) {                                                             \
      const float* smb_ = sm + (bufsel) * BUF;                                \
      float4 a0 = make_float4(0.f, 0.f, 0.f, 0.f);                            \
      float4 a1 = make_float4(0.f, 0.f, 0.f, 0.f);                            \
      _Pragma("unroll") for (int jj_ = 0; jj_ < 6; ++jj_) {                   \
        _Pragma("unroll") for (int ch_ = 0; ch_ < Cc; ++ch_) {                \
          const float* rp_ = smb_ + ch_ * CST + jj_ * RST + rdoff;            \
          const float4 A_ = *(const float4*)rp_;                              \
          const float4 B_ = *(const float4*)(rp_ + 4);                        \
          const float4 C_ = *(const float4*)(rp_ + 8);                        \
          float win_[8];                                                      \
          win_[0] = lo ? 0.f : A_.z;                                          \
          win_[1] = lo ? 0.f : A_.w;                                          \
          win_[2] = B_.x; win_[3] = B_.y; win_[4] = B_.z; win_[5] = B_.w;     \
          win_[6] = hi ? 0.f : C_.x;                                          \
          win_[7] = hi ? 0.f : C_.y;                                          \
          if (jj_ <= 4) {                                                     \
            _Pragma("unroll") for (int kx_ = 0; kx_ < 5; ++kx_) {             \
              const float wv_ = w[ch_][jj_][kx_];                             \
              a0.x = fmaf(win_[kx_ + 0], wv_, a0.x);                          \
              a0.y = fmaf(win_[kx_ + 1], wv_, a0.y);                          \
              a0.z = fmaf(win_[kx_ + 2], wv_, a0.z);                          \
              a0.w = fmaf(win_[kx_ + 3], wv_, a0.w);                          \
            }                                                                 \
          }                                                                   \
          if (jj_ >= 1) {                                                     \
            _Pragma("unroll") for (int kx_ = 0; kx_ < 5; ++kx_) {             \
              const float wv_ = w[ch_][jj_ - 1][kx_];                         \
              a1.x = fmaf(win_[kx_ + 0], wv_, a1.x);                          \
              a1.y = fmaf(win_[kx_ + 1], wv_, a1.y);                          \
              a1.z = fmaf(win_[kx_ + 2], wv_, a1.z);                          \
              a1.w = fmaf(win_[kx_ + 3], wv_, a1.w);                          \
            }                                                                 \
          }                                                                   \
        }                                                                     \
      }                                                                       \
      const int gy0_ = (bnd) * BAND + tg * 2;                                 \
      float* op_ = outn + (size_t)gy0_ * Wc + col * 4;                        \
      float4 o0, o1;                                                          \
      o0.x = a0.x + bias; o0.y = a0.y + bias;                                 \
      o0.z = a0.z + bias; o0.w = a0.w + bias;                                 \
      o1.x = a1.x + bias; o1.y = a1.y + bias;                                 \
      o1.z = a1.z + bias; o1.w = a1.w + bias;                                 \
      *(float4*)op_ = o0;                                                     \
      *(float4*)(op_ + Wc) = o1;                                              \
    }                                                                         \
  } while (0)

  // ---- double-buffered band pipeline ----
  STAGE(g * BPB, 0);
#pragma unroll 1
  for (int bb = 0; bb < BPB; ++bb) {
    const int b = g * BPB + bb;
    __syncthreads();                  // stage(bb) drained; prior compute done
    if (bb + 1 < BPB) STAGE(b + 1, (bb + 1) & 1);   // fly under compute(bb)
    COMPUTE(b, bb & 1);
  }

#undef STAGE
#undef COMPUTE
}

}  // namespace

extern "C" void kernel_launch(void* const* d_in, const int* in_sizes, int n_in,
                              void* d_out, int out_size, void* d_ws, size_t ws_size,
                              hipStream_t stream) {
  const float* x  = (const float*)d_in[0];   // [N,3,224,224] f32
  const float* wl = (const float*)d_in[1];   // [1,75] f32
  const float* b  = (const float*)d_in[2];   // [1] f32
  float* out = (float*)d_out;                // [N,224,224] f32

  const int N = out_size / HW;               // 256
  const int nblk = N * GPB;                  // 1792 = 8 * 224

  conv5x5_r13<<<nblk, BLK, 0, stream>>>(x, wl, b, out);
}

// Round 15
// 53.353 us; speedup vs baseline: 1.6706x; 1.2146x over previous
//
#include <hip/hip_runtime.h>

// Conv2d 5x5, C=3, O=1, stride 1, pad 2, N=256, H=W=224, +bias.
// R15 = R14 with the compile fix: the 6 (band,channel) phases are expanded
// explicitly with literal constants (constexpr-able; w[ch] statically indexed).
//   R13 post-mortem: (1) bank conflicts 1.16e7 invariant vs R12 -> source is
//   the STAGING writes (row strides 224/256 dw are both 0 mod 32: every row
//   starts at bank 0, concurrent row-writes collide). (2) 2 blocks/CU: a
//   block's waves are barrier-locked, no slip -> 3x over the ~20us issue floor.
// Design:
//   - phase = (band, channel): stage ch c+1 while computing ch c; acc (a0,a1)
//     carried in regs across the 3 channel phases of a band.
//   - buffer = 1 ch x 12 rows x RST=232 dw (232%32=8 -> 8-bank rotation per
//     row, de-phases concurrent staging writes). dbuf = 22272 B -> 7 blocks/CU.
//   - grid 3584 (= 14 strips x 256 images) -> 7 blocks/CU of work, ALL
//     resident: waves on a SIMD come from ~7 different blocks (slip restored).
//   - barriers every ~300 inst bound ds_read liveness -> VGPR stays small.
//   - +4-dword shifted rows (R13): window = 3 aligned b128, lo/hi cndmasks.
//   - stage: 12 rows x 56-lane gl_lds16, 3 per wave; OOB rows zero-filled.
//   - XCD swizzle (3584 = 8*448, bijective).

namespace {

constexpr int Hc = 224, Wc = 224, Cc = 3;
constexpr int HW = Hc * Wc;
constexpr int CHW = Cc * HW;
constexpr int BAND = 8;               // output rows per band
constexpr int SROWS = BAND + 4;       // 12 staged rows per (band, channel)
constexpr int RST = 232;              // LDS row stride (dwords); 232%32 = 8
constexpr int BUFD = SROWS * RST;     // 2784 dwords = 11136 B per buffer
constexpr int BPB = 2;                // bands per block
constexpr int NPH = 3 * BPB;          // 6 phases
constexpr int SPI = Hc / BAND / BPB;  // 14 strips per image
constexpr int BLK = 256;

__device__ __forceinline__ void gl_lds16(const float* g, float* l) {
  __builtin_amdgcn_global_load_lds(
      (const __attribute__((address_space(1))) void*)g,
      (__attribute__((address_space(3))) void*)l, 16, 0, 0);
}

__global__ __launch_bounds__(BLK) void conv5x5_r15(
    const float* __restrict__ x, const float* __restrict__ wl,
    const float* __restrict__ bptr, float* __restrict__ out) {
  __shared__ __align__(16) float sm[2 * BUFD];   // 22272 B

  const int tid = threadIdx.x;
  const int lane = tid & 63;
  const int wv = tid >> 6;

  // Bijective XCD swizzle: 3584 = 8 * 448.
  const int cpx = gridDim.x >> 3;
  const int bid = (blockIdx.x & 7) * cpx + (blockIdx.x >> 3);
  const int n = bid / SPI;                 // image
  const int b0 = (bid % SPI) * BPB;        // first band of this strip

  // Weights: wave-uniform, compile-time offsets -> SGPRs.
  float w[Cc][5][5];
#pragma unroll
  for (int c = 0; c < Cc; ++c)
#pragma unroll
    for (int i = 0; i < 25; ++i) w[c][i / 5][i % 5] = wl[c * 25 + i];
  const float bias = bptr[0];

  const float* xn = x + (size_t)n * CHW;
  float* outn = out + (size_t)n * HW;

  // Compute roles: 224 threads = 56 cols x 4 row-groups; thread = 4x2 outputs.
  const bool active = tid < 224;
  const int col = tid % 56;
  const int tg = tid / 56;
  const bool lo = (col == 0), hi = (col == 55);
  const int rdo = col * 4;                 // read base (dwords) within a row

  float4 a0, a1;                           // band accumulators, live across
                                           // the 3 channel phases of a band

  // Stage phase P (literal): 12 rows of channel P%3, band b0+P/3, into
  // buffer P&1. Wave wv owns rows {wv, wv+4, wv+8}. LDS dest is wave-uniform;
  // HW adds lane*16 (lanes >= 56 masked; row data = dwords 4..227, global
  // dword j at LDS dword j+4). OOB rows (y pad) zero-filled.
#define STAGE_P(P)                                                            \
  do {                                                                        \
    const int band_ = b0 + (P) / 3;                                           \
    const float* gch_ = xn + (size_t)((P) % 3) * HW;                          \
    float* smb_ = sm + ((P) & 1) * BUFD;                                      \
    _Pragma("unroll") for (int i_ = 0; i_ < 3; ++i_) {                        \
      const int r_ = wv + 4 * i_;                                             \
      const int gy_ = band_ * BAND - 2 + r_;                                  \
      float* ld_ = smb_ + r_ * RST + 4;                                       \
      if (gy_ >= 0 && gy_ < Hc) {                                             \
        if (lane < 56)                                                        \
          gl_lds16(gch_ + (size_t)gy_ * Wc + lane * 4, ld_);                  \
      } else {                                                                \
        if (lane < 56)                                                        \
          *(float4*)(ld_ + lane * 4) = make_float4(0.f, 0.f, 0.f, 0.f);       \
      }                                                                       \
    }                                                                         \
  } while (0)

  // Compute phase P (literal) from buffer P&1. Window for col = 3 aligned
  // b128: A @ dword 4c, B @ 4c+4, C @ 4c+8; win[j] = global[4c-2+j] =
  // {A.z,A.w,B.xyzw,C.x,C.y}; lo/hi masked.
#define COMPUTE_P(P)                                                          \
  do {                                                                        \
    constexpr int ch_ = (P) % 3;                                              \
    const int band_ = b0 + (P) / 3;                                           \
    const float* smb_ = sm + ((P) & 1) * BUFD;                                \
    if (ch_ == 0) {                                                           \
      a0 = make_float4(0.f, 0.f, 0.f, 0.f);                                   \
      a1 = make_float4(0.f, 0.f, 0.f, 0.f);                                   \
    }                                                                         \
    if (active) {                                                             \
      _Pragma("unroll") for (int jj_ = 0; jj_ < 6; ++jj_) {                   \
        const float* rp_ = smb_ + (tg * 2 + jj_) * RST + rdo;                 \
        const float4 A_ = *(const float4*)rp_;                                \
        const float4 B_ = *(const float4*)(rp_ + 4);                          \
        const float4 C_ = *(const float4*)(rp_ + 8);                          \
        float win_[8];                                                        \
        win_[0] = lo ? 0.f : A_.z;                                            \
        win_[1] = lo ? 0.f : A_.w;                                            \
        win_[2] = B_.x; win_[3] = B_.y; win_[4] = B_.z; win_[5] = B_.w;       \
        win_[6] = hi ? 0.f : C_.x;                                            \
        win_[7] = hi ? 0.f : C_.y;                                            \
        if (jj_ <= 4) {                                                       \
          _Pragma("unroll") for (int kx_ = 0; kx_ < 5; ++kx_) {               \
            const float wv_ = w[ch_][jj_][kx_];                               \
            a0.x = fmaf(win_[kx_ + 0], wv_, a0.x);                            \
            a0.y = fmaf(win_[kx_ + 1], wv_, a0.y);                            \
            a0.z = fmaf(win_[kx_ + 2], wv_, a0.z);                            \
            a0.w = fmaf(win_[kx_ + 3], wv_, a0.w);                            \
          }                                                                   \
        }                                                                     \
        if (jj_ >= 1) {                                                       \
          _Pragma("unroll") for (int kx_ = 0; kx_ < 5; ++kx_) {               \
            const float wv_ = w[ch_][jj_ - 1][kx_];                           \
            a1.x = fmaf(win_[kx_ + 0], wv_, a1.x);                            \
            a1.y = fmaf(win_[kx_ + 1], wv_, a1.y);                            \
            a1.z = fmaf(win_[kx_ + 2], wv_, a1.z);                            \
            a1.w = fmaf(win_[kx_ + 3], wv_, a1.w);                            \
          }                                                                   \
        }                                                                     \
      }                                                                       \
      if (ch_ == 2) {                                                         \
        const int gy0_ = band_ * BAND + tg * 2;                               \
        float* op_ = outn + (size_t)gy0_ * Wc + col * 4;                      \
        float4 o0, o1;                                                        \
        o0.x = a0.x + bias; o0.y = a0.y + bias;                               \
        o0.z = a0.z + bias; o0.w = a0.w + bias;                               \
        o1.x = a1.x + bias; o1.y = a1.y + bias;                               \
        o1.z = a1.z + bias; o1.w = a1.w + bias;                               \
        *(float4*)op_ = o0;                                                   \
        *(float4*)(op_ + Wc) = o1;                                            \
      }                                                                       \
    }                                                                         \
  } while (0)

  // ---- pipeline, phases expanded with literal constants ----
  STAGE_P(0);
  __syncthreads(); STAGE_P(1); COMPUTE_P(0);
  __syncthreads(); STAGE_P(2); COMPUTE_P(1);
  __syncthreads(); STAGE_P(3); COMPUTE_P(2);
  __syncthreads(); STAGE_P(4); COMPUTE_P(3);
  __syncthreads(); STAGE_P(5); COMPUTE_P(4);
  __syncthreads();             COMPUTE_P(5);

#undef STAGE_P
#undef COMPUTE_P
}

}  // namespace

extern "C" void kernel_launch(void* const* d_in, const int* in_sizes, int n_in,
                              void* d_out, int out_size, void* d_ws, size_t ws_size,
                              hipStream_t stream) {
  const float* x  = (const float*)d_in[0];   // [N,3,224,224] f32
  const float* wl = (const float*)d_in[1];   // [1,75] f32
  const float* b  = (const float*)d_in[2];   // [1] f32
  float* out = (float*)d_out;                // [N,224,224] f32

  const int N = out_size / HW;               // 256
  const int nblk = N * SPI;                  // 3584 = 8 * 448

  conv5x5_r15<<<nblk, BLK, 0, stream>>>(x, wl, b, out);
}